// Round 1
// baseline (2137.721 us; speedup 1.0000x reference)
//
#include <hip/hip_runtime.h>
#include <hip/hip_bf16.h>
#include <math.h>

#define BB 16
#define LL 2048
#define CIN 7
#define DM 128
#define DIN 256
#define DFF 32
#define DTR 8
#define NDBL 72   // 8 + 32 + 32

// ---------------- stats: mean/std per (b,c) over L ----------------
__global__ void k_stats(const float* __restrict__ x, float* __restrict__ stats) {
    int bc = blockIdx.x;            // 0..111
    int b = bc / CIN, c = bc % CIN;
    const float* p = x + (size_t)b * LL * CIN + c;
    float s = 0.f, s2 = 0.f;
    for (int l = threadIdx.x; l < LL; l += blockDim.x) {
        float v = p[(size_t)l * CIN];
        s += v; s2 += v * v;
    }
    #pragma unroll
    for (int m = 32; m >= 1; m >>= 1) { s += __shfl_xor(s, m, 64); s2 += __shfl_xor(s2, m, 64); }
    __shared__ float sh[2][4];
    int wid = threadIdx.x >> 6, lane = threadIdx.x & 63;
    if (lane == 0) { sh[0][wid] = s; sh[1][wid] = s2; }
    __syncthreads();
    if (threadIdx.x == 0) {
        float S = 0.f, S2 = 0.f;
        for (int w = 0; w < 4; w++) { S += sh[0][w]; S2 += sh[1][w]; }
        float mean = S / (float)LL;
        float var = S2 / (float)LL - mean * mean;
        stats[bc] = mean;
        stats[112 + bc] = sqrtf(var + 1e-5f);
    }
}

// ---------------- embedding: token conv (circular) + time proj + PE ----------------
__global__ void k_embed(const float* __restrict__ x, const float* __restrict__ xmark,
                        const float* __restrict__ tokw, const float* __restrict__ timew,
                        const float* __restrict__ stats, float* __restrict__ h) {
    int bl = blockIdx.x;
    int b = bl >> 11, l = bl & (LL - 1);
    int d = threadIdx.x;   // 128
    __shared__ float xs[3][CIN];
    if (threadIdx.x < 21) {
        int k = threadIdx.x / CIN, c = threadIdx.x % CIN;
        int ll = (l - 1 + k + LL) & (LL - 1);
        float v = x[((size_t)b * LL + ll) * CIN + c];
        xs[k][c] = (v - stats[b * CIN + c]) / stats[112 + b * CIN + c];
    }
    __syncthreads();
    float acc = 0.f;
    #pragma unroll
    for (int c = 0; c < CIN; c++)
        #pragma unroll
        for (int k = 0; k < 3; k++)
            acc += tokw[d * 21 + c * 3 + k] * xs[k][c];
    #pragma unroll
    for (int j = 0; j < 4; j++) acc += xmark[(size_t)bl * 4 + j] * timew[j * DM + d];
    // positional encoding
    float div = expf(-(float)(d & ~1) * (9.2103403719761836f / 128.f));
    float ang = (float)l * div;
    acc += (d & 1) ? cosf(ang) : sinf(ang);
    h[(size_t)bl * DM + d] = acc;
}

// ---------------- rmsnorm + in_proj GEMM (128 -> 512), split xi_raw / res ----------------
#define ROWS_IN 16
__global__ void k_rms_inproj(const float* __restrict__ h, const float* __restrict__ normw,
                             const float* __restrict__ W,  // [128,512]
                             float* __restrict__ xiraw, float* __restrict__ res) {
    __shared__ float a[ROWS_IN][DM];
    __shared__ float rms[ROWS_IN];
    int r0 = blockIdx.x * ROWS_IN;
    int t = threadIdx.x;
    for (int i = t; i < ROWS_IN * DM; i += 256)
        a[i >> 7][i & 127] = h[(size_t)(r0 + (i >> 7)) * DM + (i & 127)];
    __syncthreads();
    {   // rms per row: 16 threads per row, 8 elems each
        int r = t >> 4, p = t & 15;
        float s = 0.f;
        #pragma unroll
        for (int i = 0; i < 8; i++) { float v = a[r][p * 8 + i]; s += v * v; }
        #pragma unroll
        for (int m = 8; m >= 1; m >>= 1) s += __shfl_xor(s, m, 16);
        if (p == 0) rms[r] = rsqrtf(s / (float)DM + 1e-5f);
    }
    __syncthreads();
    for (int i = t; i < ROWS_IN * DM; i += 256) {
        int r = i >> 7, k = i & 127;
        a[r][k] *= rms[r] * normw[k];
    }
    __syncthreads();
    float acc0[ROWS_IN], acc1[ROWS_IN];
    #pragma unroll
    for (int r = 0; r < ROWS_IN; r++) { acc0[r] = 0.f; acc1[r] = 0.f; }
    for (int k = 0; k < DM; k++) {
        float w0 = W[k * 512 + t];
        float w1 = W[k * 512 + t + 256];
        #pragma unroll
        for (int r = 0; r < ROWS_IN; r++) {
            float av = a[r][k];
            acc0[r] = fmaf(av, w0, acc0[r]);
            acc1[r] = fmaf(av, w1, acc1[r]);
        }
    }
    for (int r = 0; r < ROWS_IN; r++) {
        xiraw[(size_t)(r0 + r) * DIN + t] = acc0[r];
        res  [(size_t)(r0 + r) * DIN + t] = acc1[r];
    }
}

// ---------------- depthwise causal conv (k=4) + bias + SiLU ----------------
__global__ void k_conv(const float* __restrict__ xiraw, const float* __restrict__ cw,
                       const float* __restrict__ cb, float* __restrict__ xi) {
    int bl = blockIdx.x;
    int b = bl >> 11, l = bl & (LL - 1);
    int d = threadIdx.x;   // 256
    float4 w = ((const float4*)cw)[d];
    const float* base = xiraw + (size_t)b * LL * DIN + d;
    float acc = cb[d];
    if (l >= 3) acc = fmaf(w.x, base[(size_t)(l - 3) * DIN], acc);
    if (l >= 2) acc = fmaf(w.y, base[(size_t)(l - 2) * DIN], acc);
    if (l >= 1) acc = fmaf(w.z, base[(size_t)(l - 1) * DIN], acc);
    acc = fmaf(w.w, base[(size_t)l * DIN], acc);
    float s = acc / (1.f + __expf(-acc));   // silu
    xi[(size_t)bl * DIN + d] = s;
}

// ---------------- x_proj GEMM (256 -> 72) ----------------
__global__ void k_xproj(const float* __restrict__ xi, const float* __restrict__ W, // [256,72]
                        float* __restrict__ xdbl) {
    __shared__ float a[32][DIN];   // 32 KB
    int r0 = blockIdx.x * 32;
    int t = threadIdx.x;
    for (int i = t; i < 32 * DIN; i += 256)
        a[i >> 8][i & 255] = xi[(size_t)(r0 + (i >> 8)) * DIN + (i & 255)];
    __syncthreads();
    int r = t >> 3, g = t & 7;     // 32 rows x 8 col-groups of 9
    float acc[9];
    #pragma unroll
    for (int j = 0; j < 9; j++) acc[j] = 0.f;
    for (int k = 0; k < DIN; k++) {
        float av = a[r][k];
        const float* wp = W + k * NDBL + g * 9;
        #pragma unroll
        for (int j = 0; j < 9; j++) acc[j] = fmaf(av, wp[j], acc[j]);
    }
    for (int j = 0; j < 9; j++) xdbl[(size_t)(r0 + r) * NDBL + g * 9 + j] = acc[j];
}

// ---------------- dt_proj (8 -> 256) + softplus ----------------
__global__ void k_delta(const float* __restrict__ xdbl, const float* __restrict__ dtw,
                        const float* __restrict__ dtb, float* __restrict__ delta) {
    int r0 = blockIdx.x * 8;
    int d = threadIdx.x;   // 256
    float w[DTR];
    #pragma unroll
    for (int j = 0; j < DTR; j++) w[j] = dtw[j * DIN + d];
    float bv = dtb[d];
    for (int r = r0; r < r0 + 8; r++) {
        float acc = bv;
        #pragma unroll
        for (int j = 0; j < DTR; j++) acc = fmaf(xdbl[(size_t)r * NDBL + j], w[j], acc);
        float sp = (acc > 20.f) ? acc : log1pf(__expf(acc));
        delta[(size_t)r * DIN + d] = sp;
    }
}

// ---------------- selective scan: 32 lanes = n-dim of one (b,d) channel ----------------
__global__ void k_scan(const float* __restrict__ delta, const float* __restrict__ xi,
                       const float* __restrict__ xdbl, const float* __restrict__ alog,
                       const float* __restrict__ dparam, float* __restrict__ y) {
    int b = blockIdx.x >> 5;        // 16 b  x 32 d-groups
    int dg = blockIdx.x & 31;
    int n = threadIdx.x & 31;
    int d = dg * 8 + (threadIdx.x >> 5);
    float A = -__expf(alog[d * DFF + n]);
    float Dp = dparam[d];
    size_t rowbase = (size_t)b * LL;
    float xs = 0.f;
    // prefetch l = 0
    float dv = delta[rowbase * DIN + d];
    float uv = xi[rowbase * DIN + d];
    float Bn = xdbl[rowbase * NDBL + DTR + n];
    float Cn = xdbl[rowbase * NDBL + DTR + DFF + n];
    for (int l = 0; l < LL; l++) {
        int ln = (l + 1 < LL) ? l + 1 : l;
        size_t rn = rowbase + ln;
        float dv2 = delta[rn * DIN + d];
        float uv2 = xi[rn * DIN + d];
        float Bn2 = xdbl[rn * NDBL + DTR + n];
        float Cn2 = xdbl[rn * NDBL + DTR + DFF + n];
        float dA = __expf(dv * A);
        xs = fmaf(dA, xs, (dv * uv) * Bn);
        float c = xs * Cn;
        #pragma unroll
        for (int m = 16; m >= 1; m >>= 1) c += __shfl_xor(c, m, 32);
        if (n == 0) y[(rowbase + l) * DIN + d] = c + uv * Dp;
        dv = dv2; uv = uv2; Bn = Bn2; Cn = Cn2;
    }
}

// ---------------- gate (y * silu(res)) + out_proj (256 -> 128) + residual ----------------
__global__ void k_gate_outproj(const float* __restrict__ y, const float* __restrict__ resb,
                               const float* __restrict__ W,  // [256,128]
                               float* __restrict__ h) {
    __shared__ float g[32][DIN];   // 32 KB
    int r0 = blockIdx.x * 32;
    int t = threadIdx.x;
    for (int i = t; i < 32 * DIN; i += 256) {
        int r = i >> 8, k = i & 255;
        size_t idx = (size_t)(r0 + r) * DIN + k;
        float rv = resb[idx];
        g[r][k] = y[idx] * (rv / (1.f + __expf(-rv)));
    }
    __syncthreads();
    int col = t & 127, rg = t >> 7;   // 2 row-groups of 16
    float acc[16];
    #pragma unroll
    for (int i = 0; i < 16; i++) acc[i] = 0.f;
    for (int k = 0; k < DIN; k++) {
        float w = W[k * DM + col];
        #pragma unroll
        for (int i = 0; i < 16; i++) acc[i] = fmaf(g[rg * 16 + i][k], w, acc[i]);
    }
    for (int i = 0; i < 16; i++) {
        size_t r = (size_t)r0 + rg * 16 + i;
        h[r * DM + col] += acc[i];
    }
}

// ---------------- final: rmsnorm + out_w (128 -> 7) + denorm ----------------
__global__ void k_final(const float* __restrict__ h, const float* __restrict__ onw,
                        const float* __restrict__ outw, const float* __restrict__ stats,
                        float* __restrict__ out) {
    int bl = blockIdx.x;
    int b = bl >> 11;
    int t = threadIdx.x;   // 128
    __shared__ float xn[DM];
    __shared__ float red[2];
    float v = h[(size_t)bl * DM + t];
    float s = v * v;
    #pragma unroll
    for (int m = 32; m >= 1; m >>= 1) s += __shfl_xor(s, m, 64);
    if ((t & 63) == 0) red[t >> 6] = s;
    __syncthreads();
    float rms = rsqrtf((red[0] + red[1]) / (float)DM + 1e-5f);
    xn[t] = v * rms * onw[t];
    __syncthreads();
    if (t < 112) {
        int ccol = t >> 4, p = t & 15;
        float acc = 0.f;
        #pragma unroll
        for (int i = 0; i < 8; i++) { int k = p * 8 + i; acc = fmaf(xn[k], outw[k * 7 + ccol], acc); }
        #pragma unroll
        for (int m = 8; m >= 1; m >>= 1) acc += __shfl_xor(acc, m, 16);
        if (p == 0) {
            float sd = stats[112 + b * CIN + ccol], mn = stats[b * CIN + ccol];
            out[(size_t)bl * 7 + ccol] = acc * sd + mn;
        }
    }
}

extern "C" void kernel_launch(void* const* d_in, const int* in_sizes, int n_in,
                              void* d_out, int out_size, void* d_ws, size_t ws_size,
                              hipStream_t stream) {
    const float* x_enc = (const float*)d_in[0];
    const float* xmark = (const float*)d_in[1];
    const float* tokw  = (const float*)d_in[2];
    const float* timew = (const float*)d_in[3];
    const float* normw = (const float*)d_in[4];
    const float* inw   = (const float*)d_in[5];
    const float* cw    = (const float*)d_in[6];
    const float* cb    = (const float*)d_in[7];
    const float* xpw   = (const float*)d_in[8];
    const float* dtw   = (const float*)d_in[9];
    const float* dtb   = (const float*)d_in[10];
    const float* alog  = (const float*)d_in[11];
    const float* dpar  = (const float*)d_in[12];
    const float* opw   = (const float*)d_in[13];
    const float* onw   = (const float*)d_in[14];
    const float* outw  = (const float*)d_in[15];

    float* ws = (float*)d_ws;
    const size_t BL = (size_t)BB * LL;          // 32768
    float* stats  = ws;                          // 256
    float* h      = stats + 256;                 // BL*128
    float* xiraw  = h + BL * DM;                 // BL*256  (reused as y)
    float* resb   = xiraw + BL * DIN;            // BL*256
    float* xib    = resb + BL * DIN;             // BL*256
    float* deltab = xib + BL * DIN;              // BL*256
    float* xdbl   = deltab + BL * DIN;           // BL*72

    k_stats<<<BB * CIN, 256, 0, stream>>>(x_enc, stats);
    k_embed<<<(int)BL, DM, 0, stream>>>(x_enc, xmark, tokw, timew, stats, h);

    for (int i = 0; i < 2; i++) {
        k_rms_inproj<<<(int)(BL / ROWS_IN), 256, 0, stream>>>(
            h, normw + i * DM, inw + (size_t)i * DM * 512, xiraw, resb);
        k_conv<<<(int)BL, DIN, 0, stream>>>(xiraw, cw + i * DIN * 4, cb + i * DIN, xib);
        k_xproj<<<(int)(BL / 32), 256, 0, stream>>>(xib, xpw + (size_t)i * DIN * NDBL, xdbl);
        k_delta<<<(int)(BL / 8), 256, 0, stream>>>(xdbl, dtw + i * DTR * DIN, dtb + i * DIN, deltab);
        k_scan<<<BB * 32, 256, 0, stream>>>(deltab, xib, xdbl,
                                            alog + i * DIN * DFF, dpar + i * DIN, xiraw);
        k_gate_outproj<<<(int)(BL / 32), 256, 0, stream>>>(xiraw, resb,
                                                           opw + (size_t)i * DIN * DM, h);
    }
    k_final<<<(int)BL, DM, 0, stream>>>(h, onw, outw, stats, (float*)d_out);
}

// Round 2
// 1602.150 us; speedup vs baseline: 1.3343x; 1.3343x over previous
//
#include <hip/hip_runtime.h>
#include <hip/hip_bf16.h>
#include <math.h>

#define BB 16
#define LL 2048
#define CIN 7
#define DM 128
#define DIN 256
#define DFF 32
#define DTR 8
#define NDBL 72
#define NCH 8
#define CHUNK 256   // LL / NCH

// ---------------- stats: mean/std per (b,c) over L ----------------
__global__ void k_stats(const float* __restrict__ x, float* __restrict__ stats) {
    int bc = blockIdx.x;            // 0..111
    int b = bc / CIN, c = bc % CIN;
    const float* p = x + (size_t)b * LL * CIN + c;
    float s = 0.f, s2 = 0.f;
    for (int l = threadIdx.x; l < LL; l += blockDim.x) {
        float v = p[(size_t)l * CIN];
        s += v; s2 += v * v;
    }
    #pragma unroll
    for (int m = 32; m >= 1; m >>= 1) { s += __shfl_xor(s, m, 64); s2 += __shfl_xor(s2, m, 64); }
    __shared__ float sh[2][4];
    int wid = threadIdx.x >> 6, lane = threadIdx.x & 63;
    if (lane == 0) { sh[0][wid] = s; sh[1][wid] = s2; }
    __syncthreads();
    if (threadIdx.x == 0) {
        float S = 0.f, S2 = 0.f;
        for (int w = 0; w < 4; w++) { S += sh[0][w]; S2 += sh[1][w]; }
        float mean = S / (float)LL;
        float var = S2 / (float)LL - mean * mean;
        stats[bc] = mean;
        stats[112 + bc] = sqrtf(var + 1e-5f);
    }
}

// ---------------- embedding: token conv (circular) + time proj + PE ----------------
__global__ void k_embed(const float* __restrict__ x, const float* __restrict__ xmark,
                        const float* __restrict__ tokw, const float* __restrict__ timew,
                        const float* __restrict__ stats, float* __restrict__ h) {
    int bl = blockIdx.x;
    int b = bl >> 11, l = bl & (LL - 1);
    int d = threadIdx.x;   // 128
    __shared__ float xs[3][CIN];
    if (threadIdx.x < 21) {
        int k = threadIdx.x / CIN, c = threadIdx.x % CIN;
        int ll = (l - 1 + k + LL) & (LL - 1);
        float v = x[((size_t)b * LL + ll) * CIN + c];
        xs[k][c] = (v - stats[b * CIN + c]) / stats[112 + b * CIN + c];
    }
    __syncthreads();
    float acc = 0.f;
    #pragma unroll
    for (int c = 0; c < CIN; c++)
        #pragma unroll
        for (int k = 0; k < 3; k++)
            acc += tokw[d * 21 + c * 3 + k] * xs[k][c];
    #pragma unroll
    for (int j = 0; j < 4; j++) acc += xmark[(size_t)bl * 4 + j] * timew[j * DM + d];
    float div = expf(-(float)(d & ~1) * (9.2103403719761836f / 128.f));
    float ang = (float)l * div;
    acc += (d & 1) ? cosf(ang) : sinf(ang);
    h[(size_t)bl * DM + d] = acc;
}

// ---------------- rmsnorm + in_proj GEMM (128 -> 512) ----------------
#define ROWS_IN 16
__global__ void k_rms_inproj(const float* __restrict__ h, const float* __restrict__ normw,
                             const float* __restrict__ W,  // [128,512]
                             float* __restrict__ xiraw, float* __restrict__ res) {
    __shared__ float a[ROWS_IN][DM];
    __shared__ float rms[ROWS_IN];
    int r0 = blockIdx.x * ROWS_IN;
    int t = threadIdx.x;
    for (int i = t; i < ROWS_IN * DM; i += 256)
        a[i >> 7][i & 127] = h[(size_t)(r0 + (i >> 7)) * DM + (i & 127)];
    __syncthreads();
    {
        int r = t >> 4, p = t & 15;
        float s = 0.f;
        #pragma unroll
        for (int i = 0; i < 8; i++) { float v = a[r][p * 8 + i]; s += v * v; }
        #pragma unroll
        for (int m = 8; m >= 1; m >>= 1) s += __shfl_xor(s, m, 16);
        if (p == 0) rms[r] = rsqrtf(s / (float)DM + 1e-5f);
    }
    __syncthreads();
    for (int i = t; i < ROWS_IN * DM; i += 256) {
        int r = i >> 7, k = i & 127;
        a[r][k] *= rms[r] * normw[k];
    }
    __syncthreads();
    float acc0[ROWS_IN], acc1[ROWS_IN];
    #pragma unroll
    for (int r = 0; r < ROWS_IN; r++) { acc0[r] = 0.f; acc1[r] = 0.f; }
    for (int k = 0; k < DM; k++) {
        float w0 = W[k * 512 + t];
        float w1 = W[k * 512 + t + 256];
        #pragma unroll
        for (int r = 0; r < ROWS_IN; r++) {
            float av = a[r][k];
            acc0[r] = fmaf(av, w0, acc0[r]);
            acc1[r] = fmaf(av, w1, acc1[r]);
        }
    }
    for (int r = 0; r < ROWS_IN; r++) {
        xiraw[(size_t)(r0 + r) * DIN + t] = acc0[r];
        res  [(size_t)(r0 + r) * DIN + t] = acc1[r];
    }
}

// ---------------- depthwise causal conv (k=4) + SiLU -> transposed xiT [b,d,l] ----------------
__global__ void k_conv(const float* __restrict__ xiraw, const float* __restrict__ cw,
                       const float* __restrict__ cb, float* __restrict__ xiT) {
    __shared__ float lds[32][257];
    int blk = blockIdx.x;            // b*64 + tile
    int b = blk >> 6, tile = blk & 63;
    int l0 = tile * 32;
    int t = threadIdx.x;             // 256 = d
    float4 w = ((const float4*)cw)[t];
    float bias = cb[t];
    const float* base = xiraw + ((size_t)b * LL) * DIN + t;
    float w0 = 0.f, w1 = 0.f, w2 = 0.f;
    if (tile > 0) {
        w0 = base[(size_t)(l0 - 3) * DIN];
        w1 = base[(size_t)(l0 - 2) * DIN];
        w2 = base[(size_t)(l0 - 1) * DIN];
    }
    for (int ll = 0; ll < 32; ++ll) {
        float cur = base[(size_t)(l0 + ll) * DIN];
        float acc = fmaf(w.x, w0, bias);
        acc = fmaf(w.y, w1, acc);
        acc = fmaf(w.z, w2, acc);
        acc = fmaf(w.w, cur, acc);
        lds[ll][t] = acc / (1.f + __expf(-acc));
        w0 = w1; w1 = w2; w2 = cur;
    }
    __syncthreads();
    for (int idx = t; idx < 2048; idx += 256) {
        int d = idx >> 3, li = (idx & 7) * 4;
        float4 v = { lds[li][d], lds[li + 1][d], lds[li + 2][d], lds[li + 3][d] };
        *(float4*)(xiT + ((size_t)(b * DIN + d)) * LL + l0 + li) = v;
    }
}

// ---------------- x_proj GEMM (256 -> 72) from xiT; emits dt, BT, CT ----------------
__global__ void k_xproj(const float* __restrict__ xiT, const float* __restrict__ W,
                        float* __restrict__ dtbuf, float* __restrict__ BT,
                        float* __restrict__ CT) {
    __shared__ float a[32][257];
    int blk = blockIdx.x;
    int b = blk >> 6, tile = blk & 63;
    int l0 = tile * 32;
    int t = threadIdx.x;
    for (int idx = t; idx < 2048; idx += 256) {
        int k = idx >> 3, li = (idx & 7) * 4;
        float4 v = *(const float4*)(xiT + ((size_t)(b * DIN + k)) * LL + l0 + li);
        a[li][k] = v.x; a[li + 1][k] = v.y; a[li + 2][k] = v.z; a[li + 3][k] = v.w;
    }
    __syncthreads();
    int r = t >> 3, g = t & 7;
    float acc[9];
    #pragma unroll
    for (int j = 0; j < 9; j++) acc[j] = 0.f;
    for (int k = 0; k < DIN; k++) {
        float av = a[r][k];
        const float* wp = W + k * NDBL + g * 9;
        #pragma unroll
        for (int j = 0; j < 9; j++) acc[j] = fmaf(av, wp[j], acc[j]);
    }
    size_t row = (size_t)b * LL + l0 + r;
    #pragma unroll
    for (int j = 0; j < 9; j++) {
        int cg = g * 9 + j;
        float v = acc[j];
        if (cg < DTR)            dtbuf[row * DTR + cg] = v;
        else if (cg < DTR + DFF) BT[((size_t)(b * DFF + cg - DTR)) * LL + l0 + r] = v;
        else                     CT[((size_t)(b * DFF + cg - DTR - DFF)) * LL + l0 + r] = v;
    }
}

// ---------------- dt_proj (8 -> 256) + softplus -> transposed deltaT [b,d,l] ----------------
__global__ void k_delta(const float* __restrict__ dtbuf, const float* __restrict__ dtw,
                        const float* __restrict__ dtb, float* __restrict__ dT) {
    __shared__ float lds[32][257];
    __shared__ float dts[32][8];
    int blk = blockIdx.x;
    int b = blk >> 6, tile = blk & 63;
    int l0 = tile * 32;
    int t = threadIdx.x;
    dts[t >> 3][t & 7] = dtbuf[((size_t)b * LL + l0) * DTR + t];
    float wv[DTR];
    #pragma unroll
    for (int j = 0; j < DTR; j++) wv[j] = dtw[j * DIN + t];
    float bias = dtb[t];
    __syncthreads();
    for (int ll = 0; ll < 32; ++ll) {
        float acc = bias;
        #pragma unroll
        for (int j = 0; j < DTR; j++) acc = fmaf(dts[ll][j], wv[j], acc);
        lds[ll][t] = (acc > 20.f) ? acc : log1pf(__expf(acc));
    }
    __syncthreads();
    for (int idx = t; idx < 2048; idx += 256) {
        int d = idx >> 3, li = (idx & 7) * 4;
        float4 v = { lds[li][d], lds[li + 1][d], lds[li + 2][d], lds[li + 3][d] };
        *(float4*)(dT + ((size_t)(b * DIN + d)) * LL + l0 + li) = v;
    }
}

// ---------------- scan pass 1: per-chunk product + local final state ----------------
__global__ void k_scan_p1(const float* __restrict__ dT, const float* __restrict__ uT,
                          const float* __restrict__ BT, const float* __restrict__ alog,
                          float* __restrict__ Pb, float* __restrict__ Xfb) {
    int blk = blockIdx.x;                 // ((b*32 + dg)*NCH + c)
    int c = blk & (NCH - 1);
    int dg = (blk >> 3) & 31;
    int b = blk >> 8;
    int t = threadIdx.x;
    int n = t & 31, sub = t >> 5;
    int d = dg * 8 + sub;
    float A = -__expf(alog[d * DFF + n]);
    const float* dp = dT + ((size_t)(b * DIN + d)) * LL + c * CHUNK;
    const float* up = uT + ((size_t)(b * DIN + d)) * LL + c * CHUNK;
    const float* Bp = BT + ((size_t)(b * DFF + n)) * LL + c * CHUNK;
    float xs = 0.f, P = 1.f;
    float4 dv = *(const float4*)dp, uv = *(const float4*)up, Bv = *(const float4*)Bp;
    for (int it = 0; it < CHUNK / 4; ++it) {
        int pit = (it + 1 < CHUNK / 4) ? it + 1 : it;
        float4 dv2 = *(const float4*)(dp + pit * 4);
        float4 uv2 = *(const float4*)(up + pit * 4);
        float4 Bv2 = *(const float4*)(Bp + pit * 4);
        #define S1(X) { float dA = __expf(dv.X * A); xs = fmaf(dA, xs, dv.X * uv.X * Bv.X); P *= dA; }
        S1(x) S1(y) S1(z) S1(w)
        #undef S1
        dv = dv2; uv = uv2; Bv = Bv2;
    }
    size_t o = ((size_t)((b * NCH + c) * DIN + d)) * DFF + n;
    Pb[o] = P; Xfb[o] = xs;
}

// ---------------- scan pass 2: combine chunk carries (in-place: Xfb becomes carry-in) ----------------
__global__ void k_scan_p2(const float* __restrict__ Pb, float* __restrict__ Xfb) {
    int idx = blockIdx.x * 256 + threadIdx.x;   // 16*8192
    int b = idx >> 13;
    int dn = idx & 8191;
    float carry = 0.f;
    for (int c = 0; c < NCH; ++c) {
        size_t o = ((size_t)(b * NCH + c) << 13) + dn;
        float P = Pb[o], xf = Xfb[o];
        Xfb[o] = carry;
        carry = fmaf(P, carry, xf);
    }
}

// ---------------- scan pass 3: full scan per chunk with carry, write yT [b,d,l] ----------------
__global__ void k_scan_p3(const float* __restrict__ dT, const float* __restrict__ uT,
                          const float* __restrict__ BT, const float* __restrict__ CT,
                          const float* __restrict__ Xfb, const float* __restrict__ alog,
                          const float* __restrict__ dparam, float* __restrict__ yT) {
    int blk = blockIdx.x;
    int c = blk & (NCH - 1);
    int dg = (blk >> 3) & 31;
    int b = blk >> 8;
    int t = threadIdx.x;
    int n = t & 31, sub = t >> 5;
    int d = dg * 8 + sub;
    float A = -__expf(alog[d * DFF + n]);
    float Dp = dparam[d];
    const float* dp = dT + ((size_t)(b * DIN + d)) * LL + c * CHUNK;
    const float* up = uT + ((size_t)(b * DIN + d)) * LL + c * CHUNK;
    const float* Bp = BT + ((size_t)(b * DFF + n)) * LL + c * CHUNK;
    const float* Cp = CT + ((size_t)(b * DFF + n)) * LL + c * CHUNK;
    float* yp = yT + ((size_t)(b * DIN + d)) * LL + c * CHUNK;
    size_t o = ((size_t)((b * NCH + c) * DIN + d)) * DFF + n;
    float xs = Xfb[o];
    float4 dv = *(const float4*)dp, uv = *(const float4*)up;
    float4 Bv = *(const float4*)Bp, Cv = *(const float4*)Cp;
    for (int it = 0; it < CHUNK / 4; ++it) {
        int pit = (it + 1 < CHUNK / 4) ? it + 1 : it;
        float4 dv2 = *(const float4*)(dp + pit * 4);
        float4 uv2 = *(const float4*)(up + pit * 4);
        float4 Bv2 = *(const float4*)(Bp + pit * 4);
        float4 Cv2 = *(const float4*)(Cp + pit * 4);
        float4 y4;
        #define S2(X) { float dA = __expf(dv.X * A); xs = fmaf(dA, xs, dv.X * uv.X * Bv.X); \
                        float cc = xs * Cv.X; \
                        cc += __shfl_xor(cc, 16, 32); cc += __shfl_xor(cc, 8, 32); \
                        cc += __shfl_xor(cc, 4, 32);  cc += __shfl_xor(cc, 2, 32); \
                        cc += __shfl_xor(cc, 1, 32); \
                        y4.X = fmaf(uv.X, Dp, cc); }
        S2(x) S2(y) S2(z) S2(w)
        #undef S2
        if (n == 0) *(float4*)(yp + it * 4) = y4;
        dv = dv2; uv = uv2; Bv = Bv2; Cv = Cv2;
    }
}

// ---------------- gate (y * silu(res)) + out_proj (256 -> 128) + residual ----------------
__global__ void k_gate_outproj(const float* __restrict__ yT, const float* __restrict__ resb,
                               const float* __restrict__ W,  // [256,128]
                               float* __restrict__ h) {
    __shared__ float g[32][257];
    int blk = blockIdx.x;
    int b = blk >> 6, tile = blk & 63;
    int l0 = tile * 32;
    int t = threadIdx.x;
    for (int idx = t; idx < 2048; idx += 256) {
        int k = idx >> 3, li = (idx & 7) * 4;
        float4 v = *(const float4*)(yT + ((size_t)(b * DIN + k)) * LL + l0 + li);
        g[li][k] = v.x; g[li + 1][k] = v.y; g[li + 2][k] = v.z; g[li + 3][k] = v.w;
    }
    __syncthreads();
    for (int i = t; i < 32 * DIN; i += 256) {
        int r = i >> 8, k = i & 255;
        float rv = resb[((size_t)b * LL + l0 + r) * DIN + k];
        g[r][k] *= rv / (1.f + __expf(-rv));
    }
    __syncthreads();
    int col = t & 127, rg = t >> 7;
    float acc[16];
    #pragma unroll
    for (int i = 0; i < 16; i++) acc[i] = 0.f;
    for (int k = 0; k < DIN; k++) {
        float w = W[k * DM + col];
        #pragma unroll
        for (int i = 0; i < 16; i++) acc[i] = fmaf(g[rg * 16 + i][k], w, acc[i]);
    }
    for (int i = 0; i < 16; i++) {
        size_t r = (size_t)b * LL + l0 + rg * 16 + i;
        h[r * DM + col] += acc[i];
    }
}

// ---------------- final: rmsnorm + out_w (128 -> 7) + denorm ----------------
__global__ void k_final(const float* __restrict__ h, const float* __restrict__ onw,
                        const float* __restrict__ outw, const float* __restrict__ stats,
                        float* __restrict__ out) {
    int bl = blockIdx.x;
    int b = bl >> 11;
    int t = threadIdx.x;   // 128
    __shared__ float xn[DM];
    __shared__ float red[2];
    float v = h[(size_t)bl * DM + t];
    float s = v * v;
    #pragma unroll
    for (int m = 32; m >= 1; m >>= 1) s += __shfl_xor(s, m, 64);
    if ((t & 63) == 0) red[t >> 6] = s;
    __syncthreads();
    float rms = rsqrtf((red[0] + red[1]) / (float)DM + 1e-5f);
    xn[t] = v * rms * onw[t];
    __syncthreads();
    if (t < 112) {
        int ccol = t >> 4, p = t & 15;
        float acc = 0.f;
        #pragma unroll
        for (int i = 0; i < 8; i++) { int k = p * 8 + i; acc = fmaf(xn[k], outw[k * 7 + ccol], acc); }
        #pragma unroll
        for (int m = 8; m >= 1; m >>= 1) acc += __shfl_xor(acc, m, 16);
        if (p == 0) {
            float sd = stats[112 + b * CIN + ccol], mn = stats[b * CIN + ccol];
            out[(size_t)bl * 7 + ccol] = acc * sd + mn;
        }
    }
}

extern "C" void kernel_launch(void* const* d_in, const int* in_sizes, int n_in,
                              void* d_out, int out_size, void* d_ws, size_t ws_size,
                              hipStream_t stream) {
    const float* x_enc = (const float*)d_in[0];
    const float* xmark = (const float*)d_in[1];
    const float* tokw  = (const float*)d_in[2];
    const float* timew = (const float*)d_in[3];
    const float* normw = (const float*)d_in[4];
    const float* inw   = (const float*)d_in[5];
    const float* cw    = (const float*)d_in[6];
    const float* cb    = (const float*)d_in[7];
    const float* xpw   = (const float*)d_in[8];
    const float* dtw   = (const float*)d_in[9];
    const float* dtb   = (const float*)d_in[10];
    const float* alog  = (const float*)d_in[11];
    const float* dpar  = (const float*)d_in[12];
    const float* opw   = (const float*)d_in[13];
    const float* onw   = (const float*)d_in[14];
    const float* outw  = (const float*)d_in[15];

    float* ws = (float*)d_ws;
    const size_t BL = (size_t)BB * LL;          // 32768
    float* stats  = ws;                          // 256
    float* h      = stats + 256;                 // BL*128
    float* xiraw  = h + BL * DM;                 // BL*256  (reused as yT)
    float* resb   = xiraw + BL * DIN;            // BL*256
    float* xiT    = resb + BL * DIN;             // BL*256  [b,d,l]
    float* deltaT = xiT + BL * DIN;              // BL*256  [b,d,l]
    float* dtbuf  = deltaT + BL * DIN;           // BL*8
    float* BT     = dtbuf + BL * DTR;            // BL*32   [b,n,l]
    float* CT     = BT + BL * DFF;               // BL*32   [b,n,l]
    float* Pb     = CT + BL * DFF;               // 16*NCH*8192
    float* Xfb    = Pb + (size_t)BB * NCH * DIN * DFF;

    k_stats<<<BB * CIN, 256, 0, stream>>>(x_enc, stats);
    k_embed<<<(int)BL, DM, 0, stream>>>(x_enc, xmark, tokw, timew, stats, h);

    for (int i = 0; i < 2; i++) {
        k_rms_inproj<<<(int)(BL / ROWS_IN), 256, 0, stream>>>(
            h, normw + i * DM, inw + (size_t)i * DM * 512, xiraw, resb);
        k_conv<<<BB * 64, 256, 0, stream>>>(xiraw, cw + i * DIN * 4, cb + i * DIN, xiT);
        k_xproj<<<BB * 64, 256, 0, stream>>>(xiT, xpw + (size_t)i * DIN * NDBL, dtbuf, BT, CT);
        k_delta<<<BB * 64, 256, 0, stream>>>(dtbuf, dtw + i * DTR * DIN, dtb + i * DIN, deltaT);
        k_scan_p1<<<BB * 32 * NCH, 256, 0, stream>>>(deltaT, xiT, BT,
                                                     alog + i * DIN * DFF, Pb, Xfb);
        k_scan_p2<<<BB * 8192 / 256, 256, 0, stream>>>(Pb, Xfb);
        k_scan_p3<<<BB * 32 * NCH, 256, 0, stream>>>(deltaT, xiT, BT, CT, Xfb,
                                                     alog + i * DIN * DFF, dpar + i * DIN, xiraw);
        k_gate_outproj<<<BB * 64, 256, 0, stream>>>(xiraw, resb,
                                                    opw + (size_t)i * DIN * DM, h);
    }
    k_final<<<(int)BL, DM, 0, stream>>>(h, onw, outw, stats, (float*)d_out);
}

// Round 3
// 878.442 us; speedup vs baseline: 2.4335x; 1.8239x over previous
//
#include <hip/hip_runtime.h>
#include <hip/hip_bf16.h>
#include <math.h>

#define BB 16
#define LL 2048
#define CIN 7
#define DM 128
#define DIN 256
#define DFF 32
#define DTR 8
#define NDBL 72
#define NCH 32
#define CHUNK 64   // LL / NCH

// ---------------- stats: mean/std per (b,c) over L ----------------
__global__ void k_stats(const float* __restrict__ x, float* __restrict__ stats) {
    int bc = blockIdx.x;            // 0..111
    int b = bc / CIN, c = bc % CIN;
    const float* p = x + (size_t)b * LL * CIN + c;
    float s = 0.f, s2 = 0.f;
    for (int l = threadIdx.x; l < LL; l += blockDim.x) {
        float v = p[(size_t)l * CIN];
        s += v; s2 += v * v;
    }
    #pragma unroll
    for (int m = 32; m >= 1; m >>= 1) { s += __shfl_xor(s, m, 64); s2 += __shfl_xor(s2, m, 64); }
    __shared__ float sh[2][4];
    int wid = threadIdx.x >> 6, lane = threadIdx.x & 63;
    if (lane == 0) { sh[0][wid] = s; sh[1][wid] = s2; }
    __syncthreads();
    if (threadIdx.x == 0) {
        float S = 0.f, S2 = 0.f;
        for (int w = 0; w < 4; w++) { S += sh[0][w]; S2 += sh[1][w]; }
        float mean = S / (float)LL;
        float var = S2 / (float)LL - mean * mean;
        stats[bc] = mean;
        stats[112 + bc] = sqrtf(var + 1e-5f);
    }
}

// ---------------- embedding: token conv (circular) + time proj + PE ----------------
__global__ void k_embed(const float* __restrict__ x, const float* __restrict__ xmark,
                        const float* __restrict__ tokw, const float* __restrict__ timew,
                        const float* __restrict__ stats, float* __restrict__ h) {
    int bl = blockIdx.x;
    int b = bl >> 11, l = bl & (LL - 1);
    int d = threadIdx.x;   // 128
    __shared__ float xs[3][CIN];
    if (threadIdx.x < 21) {
        int k = threadIdx.x / CIN, c = threadIdx.x % CIN;
        int ll = (l - 1 + k + LL) & (LL - 1);
        float v = x[((size_t)b * LL + ll) * CIN + c];
        xs[k][c] = (v - stats[b * CIN + c]) / stats[112 + b * CIN + c];
    }
    __syncthreads();
    float acc = 0.f;
    #pragma unroll
    for (int c = 0; c < CIN; c++)
        #pragma unroll
        for (int k = 0; k < 3; k++)
            acc += tokw[d * 21 + c * 3 + k] * xs[k][c];
    #pragma unroll
    for (int j = 0; j < 4; j++) acc += xmark[(size_t)bl * 4 + j] * timew[j * DM + d];
    float div = expf(-(float)(d & ~1) * (9.2103403719761836f / 128.f));
    float ang = (float)l * div;
    acc += (d & 1) ? cosf(ang) : sinf(ang);
    h[(size_t)bl * DM + d] = acc;
}

// ---------------- rmsnorm + in_proj GEMM (128 -> 512) ----------------
#define ROWS_IN 16
__global__ void k_rms_inproj(const float* __restrict__ h, const float* __restrict__ normw,
                             const float* __restrict__ W,  // [128,512]
                             float* __restrict__ xiraw, float* __restrict__ res) {
    __shared__ float a[ROWS_IN][DM];
    __shared__ float rms[ROWS_IN];
    int r0 = blockIdx.x * ROWS_IN;
    int t = threadIdx.x;
    for (int i = t; i < ROWS_IN * DM; i += 256)
        a[i >> 7][i & 127] = h[(size_t)(r0 + (i >> 7)) * DM + (i & 127)];
    __syncthreads();
    {
        int r = t >> 4, p = t & 15;
        float s = 0.f;
        #pragma unroll
        for (int i = 0; i < 8; i++) { float v = a[r][p * 8 + i]; s += v * v; }
        #pragma unroll
        for (int m = 8; m >= 1; m >>= 1) s += __shfl_xor(s, m, 16);
        if (p == 0) rms[r] = rsqrtf(s / (float)DM + 1e-5f);
    }
    __syncthreads();
    for (int i = t; i < ROWS_IN * DM; i += 256) {
        int r = i >> 7, k = i & 127;
        a[r][k] *= rms[r] * normw[k];
    }
    __syncthreads();
    float acc0[ROWS_IN], acc1[ROWS_IN];
    #pragma unroll
    for (int r = 0; r < ROWS_IN; r++) { acc0[r] = 0.f; acc1[r] = 0.f; }
    for (int k = 0; k < DM; k++) {
        float w0 = W[k * 512 + t];
        float w1 = W[k * 512 + t + 256];
        #pragma unroll
        for (int r = 0; r < ROWS_IN; r++) {
            float av = a[r][k];
            acc0[r] = fmaf(av, w0, acc0[r]);
            acc1[r] = fmaf(av, w1, acc1[r]);
        }
    }
    for (int r = 0; r < ROWS_IN; r++) {
        xiraw[(size_t)(r0 + r) * DIN + t] = acc0[r];
        res  [(size_t)(r0 + r) * DIN + t] = acc1[r];
    }
}

// ---------------- depthwise causal conv (k=4) + SiLU -> transposed xiT [b,d,l] ----------------
__global__ void k_conv(const float* __restrict__ xiraw, const float* __restrict__ cw,
                       const float* __restrict__ cb, float* __restrict__ xiT) {
    __shared__ float lds[32][257];
    int blk = blockIdx.x;            // b*64 + tile
    int b = blk >> 6, tile = blk & 63;
    int l0 = tile * 32;
    int t = threadIdx.x;             // 256 = d
    float4 w = ((const float4*)cw)[t];
    float bias = cb[t];
    const float* base = xiraw + ((size_t)b * LL) * DIN + t;
    float w0 = 0.f, w1 = 0.f, w2 = 0.f;
    if (tile > 0) {
        w0 = base[(size_t)(l0 - 3) * DIN];
        w1 = base[(size_t)(l0 - 2) * DIN];
        w2 = base[(size_t)(l0 - 1) * DIN];
    }
    for (int ll = 0; ll < 32; ++ll) {
        float cur = base[(size_t)(l0 + ll) * DIN];
        float acc = fmaf(w.x, w0, bias);
        acc = fmaf(w.y, w1, acc);
        acc = fmaf(w.z, w2, acc);
        acc = fmaf(w.w, cur, acc);
        lds[ll][t] = acc / (1.f + __expf(-acc));
        w0 = w1; w1 = w2; w2 = cur;
    }
    __syncthreads();
    for (int idx = t; idx < 2048; idx += 256) {
        int d = idx >> 3, li = (idx & 7) * 4;
        float4 v = { lds[li][d], lds[li + 1][d], lds[li + 2][d], lds[li + 3][d] };
        *(float4*)(xiT + ((size_t)(b * DIN + d)) * LL + l0 + li) = v;
    }
}

// ---------------- x_proj GEMM (256 -> 72) from xiT; emits dt, BT, CT ----------------
__global__ void k_xproj(const float* __restrict__ xiT, const float* __restrict__ W,
                        float* __restrict__ dtbuf, float* __restrict__ BT,
                        float* __restrict__ CT) {
    __shared__ float a[32][257];
    int blk = blockIdx.x;
    int b = blk >> 6, tile = blk & 63;
    int l0 = tile * 32;
    int t = threadIdx.x;
    for (int idx = t; idx < 2048; idx += 256) {
        int k = idx >> 3, li = (idx & 7) * 4;
        float4 v = *(const float4*)(xiT + ((size_t)(b * DIN + k)) * LL + l0 + li);
        a[li][k] = v.x; a[li + 1][k] = v.y; a[li + 2][k] = v.z; a[li + 3][k] = v.w;
    }
    __syncthreads();
    int r = t >> 3, g = t & 7;
    float acc[9];
    #pragma unroll
    for (int j = 0; j < 9; j++) acc[j] = 0.f;
    for (int k = 0; k < DIN; k++) {
        float av = a[r][k];
        const float* wp = W + k * NDBL + g * 9;
        #pragma unroll
        for (int j = 0; j < 9; j++) acc[j] = fmaf(av, wp[j], acc[j]);
    }
    size_t row = (size_t)b * LL + l0 + r;
    #pragma unroll
    for (int j = 0; j < 9; j++) {
        int cg = g * 9 + j;
        float v = acc[j];
        if (cg < DTR)            dtbuf[row * DTR + cg] = v;
        else if (cg < DTR + DFF) BT[((size_t)(b * DFF + cg - DTR)) * LL + l0 + r] = v;
        else                     CT[((size_t)(b * DFF + cg - DTR - DFF)) * LL + l0 + r] = v;
    }
}

// ---------------- dt_proj (8 -> 256) + softplus -> transposed deltaT [b,d,l] ----------------
__global__ void k_delta(const float* __restrict__ dtbuf, const float* __restrict__ dtw,
                        const float* __restrict__ dtb, float* __restrict__ dT) {
    __shared__ float lds[32][257];
    __shared__ float dts[32][8];
    int blk = blockIdx.x;
    int b = blk >> 6, tile = blk & 63;
    int l0 = tile * 32;
    int t = threadIdx.x;
    dts[t >> 3][t & 7] = dtbuf[((size_t)b * LL + l0) * DTR + t];
    float wv[DTR];
    #pragma unroll
    for (int j = 0; j < DTR; j++) wv[j] = dtw[j * DIN + t];
    float bias = dtb[t];
    __syncthreads();
    for (int ll = 0; ll < 32; ++ll) {
        float acc = bias;
        #pragma unroll
        for (int j = 0; j < DTR; j++) acc = fmaf(dts[ll][j], wv[j], acc);
        lds[ll][t] = (acc > 20.f) ? acc : log1pf(__expf(acc));
    }
    __syncthreads();
    for (int idx = t; idx < 2048; idx += 256) {
        int d = idx >> 3, li = (idx & 7) * 4;
        float4 v = { lds[li][d], lds[li + 1][d], lds[li + 2][d], lds[li + 3][d] };
        *(float4*)(dT + ((size_t)(b * DIN + d)) * LL + l0 + li) = v;
    }
}

// ---------------- scan pass 1: 8 states/thread, B staged in LDS ----------------
// block: 256 thr = 64 d x 4 quads; blk = ((b*NCH + c)*4 + dblk)
__global__ void k_scan_p1(const float* __restrict__ dT, const float* __restrict__ uT,
                          const float* __restrict__ BT, const float* __restrict__ alog,
                          float* __restrict__ Pb, float* __restrict__ Xfb) {
    __shared__ float sB[CHUNK][32];
    int blk = blockIdx.x;
    int dblk = blk & 3;
    int c = (blk >> 2) & (NCH - 1);
    int b = blk >> 7;
    int t = threadIdx.x;
    int q = t & 3, dloc = t >> 2;
    int d = dblk * 64 + dloc;
    int l0 = c * CHUNK;
    for (int idx = t; idx < 32 * (CHUNK / 4); idx += 256) {
        int n = idx >> 4, lf = idx & 15;
        float4 v = *(const float4*)(BT + ((size_t)(b * DFF + n)) * LL + l0 + lf * 4);
        sB[lf * 4 + 0][n] = v.x; sB[lf * 4 + 1][n] = v.y;
        sB[lf * 4 + 2][n] = v.z; sB[lf * 4 + 3][n] = v.w;
    }
    float A2[8];
    {
        const float* ap = alog + d * DFF + q * 8;
        #pragma unroll
        for (int k = 0; k < 8; k++) A2[k] = -__expf(ap[k]) * 1.4426950408889634f;
    }
    const float* dp = dT + ((size_t)(b * DIN + d)) * LL + l0;
    const float* up = uT + ((size_t)(b * DIN + d)) * LL + l0;
    float4 dv = *(const float4*)dp, uv = *(const float4*)up;
    float xs[8] = {0, 0, 0, 0, 0, 0, 0, 0};
    float sdv = 0.f;
    const float* sBq = &sB[0][0] + q * 8;
    __syncthreads();
    for (int it = 0; it < CHUNK / 4; ++it) {
        int pit = (it + 1 < CHUNK / 4) ? it + 1 : it;
        float4 dvn = *(const float4*)(dp + pit * 4);
        float4 uvn = *(const float4*)(up + pit * 4);
        int lb = it * 4;
#define STEP1(X, J) { \
        float dvx = dv.X; sdv += dvx; float t1 = dvx * uv.X; \
        const float4* bp = (const float4*)(sBq + (lb + J) * 32); \
        float4 b0 = bp[0], b1 = bp[1]; \
        float e; \
        e = __builtin_amdgcn_exp2f(dvx * A2[0]); xs[0] = fmaf(e, xs[0], t1 * b0.x); \
        e = __builtin_amdgcn_exp2f(dvx * A2[1]); xs[1] = fmaf(e, xs[1], t1 * b0.y); \
        e = __builtin_amdgcn_exp2f(dvx * A2[2]); xs[2] = fmaf(e, xs[2], t1 * b0.z); \
        e = __builtin_amdgcn_exp2f(dvx * A2[3]); xs[3] = fmaf(e, xs[3], t1 * b0.w); \
        e = __builtin_amdgcn_exp2f(dvx * A2[4]); xs[4] = fmaf(e, xs[4], t1 * b1.x); \
        e = __builtin_amdgcn_exp2f(dvx * A2[5]); xs[5] = fmaf(e, xs[5], t1 * b1.y); \
        e = __builtin_amdgcn_exp2f(dvx * A2[6]); xs[6] = fmaf(e, xs[6], t1 * b1.z); \
        e = __builtin_amdgcn_exp2f(dvx * A2[7]); xs[7] = fmaf(e, xs[7], t1 * b1.w); }
        STEP1(x, 0) STEP1(y, 1) STEP1(z, 2) STEP1(w, 3)
#undef STEP1
        dv = dvn; uv = uvn;
    }
    size_t o = ((size_t)((b * NCH + c) * DIN + d)) * DFF + q * 8;
    float4 P0, P1, X0, X1;
    P0.x = __builtin_amdgcn_exp2f(A2[0] * sdv); P0.y = __builtin_amdgcn_exp2f(A2[1] * sdv);
    P0.z = __builtin_amdgcn_exp2f(A2[2] * sdv); P0.w = __builtin_amdgcn_exp2f(A2[3] * sdv);
    P1.x = __builtin_amdgcn_exp2f(A2[4] * sdv); P1.y = __builtin_amdgcn_exp2f(A2[5] * sdv);
    P1.z = __builtin_amdgcn_exp2f(A2[6] * sdv); P1.w = __builtin_amdgcn_exp2f(A2[7] * sdv);
    X0.x = xs[0]; X0.y = xs[1]; X0.z = xs[2]; X0.w = xs[3];
    X1.x = xs[4]; X1.y = xs[5]; X1.z = xs[6]; X1.w = xs[7];
    *(float4*)(Pb + o) = P0;  *(float4*)(Pb + o + 4) = P1;
    *(float4*)(Xfb + o) = X0; *(float4*)(Xfb + o + 4) = X1;
}

// ---------------- scan pass 2: combine chunk carries ----------------
__global__ void k_scan_p2(const float* __restrict__ Pb, float* __restrict__ Xfb) {
    int idx = blockIdx.x * 256 + threadIdx.x;   // 16*8192
    int b = idx >> 13;
    int dn = idx & 8191;
    float carry = 0.f;
    #pragma unroll
    for (int c = 0; c < NCH; ++c) {
        size_t o = ((size_t)(b * NCH + c) << 13) + dn;
        float P = Pb[o], xf = Xfb[o];
        Xfb[o] = carry;
        carry = fmaf(P, carry, xf);
    }
}

// ---------------- scan pass 3: 8 states/thread, B/C in LDS, quad-reduce y ----------------
__global__ void k_scan_p3(const float* __restrict__ dT, const float* __restrict__ uT,
                          const float* __restrict__ BT, const float* __restrict__ CT,
                          const float* __restrict__ Xfb, const float* __restrict__ alog,
                          const float* __restrict__ dparam, float* __restrict__ yT) {
    __shared__ float sB[CHUNK][32];
    __shared__ float sC[CHUNK][32];
    int blk = blockIdx.x;
    int dblk = blk & 3;
    int c = (blk >> 2) & (NCH - 1);
    int b = blk >> 7;
    int t = threadIdx.x;
    int q = t & 3, dloc = t >> 2;
    int d = dblk * 64 + dloc;
    int l0 = c * CHUNK;
    for (int idx = t; idx < 2 * 32 * (CHUNK / 4); idx += 256) {
        int sel = idx >> 9, r = idx & 511;
        int n = r >> 4, lf = r & 15;
        const float* src = (sel ? CT : BT) + ((size_t)(b * DFF + n)) * LL + l0 + lf * 4;
        float4 v = *(const float4*)src;
        if (sel) { sC[lf*4+0][n] = v.x; sC[lf*4+1][n] = v.y; sC[lf*4+2][n] = v.z; sC[lf*4+3][n] = v.w; }
        else     { sB[lf*4+0][n] = v.x; sB[lf*4+1][n] = v.y; sB[lf*4+2][n] = v.z; sB[lf*4+3][n] = v.w; }
    }
    float A2[8];
    {
        const float* ap = alog + d * DFF + q * 8;
        #pragma unroll
        for (int k = 0; k < 8; k++) A2[k] = -__expf(ap[k]) * 1.4426950408889634f;
    }
    float Dp = dparam[d];
    const float* dp = dT + ((size_t)(b * DIN + d)) * LL + l0;
    const float* up = uT + ((size_t)(b * DIN + d)) * LL + l0;
    float* yp = yT + ((size_t)(b * DIN + d)) * LL + l0;
    size_t o = ((size_t)((b * NCH + c) * DIN + d)) * DFF + q * 8;
    float4 x0 = *(const float4*)(Xfb + o), x1 = *(const float4*)(Xfb + o + 4);
    float xs[8] = {x0.x, x0.y, x0.z, x0.w, x1.x, x1.y, x1.z, x1.w};
    float4 dv = *(const float4*)dp, uv = *(const float4*)up;
    const float* sBq = &sB[0][0] + q * 8;
    const float* sCq = &sC[0][0] + q * 8;
    __syncthreads();
    for (int it = 0; it < CHUNK / 4; ++it) {
        int pit = (it + 1 < CHUNK / 4) ? it + 1 : it;
        float4 dvn = *(const float4*)(dp + pit * 4);
        float4 uvn = *(const float4*)(up + pit * 4);
        int lb = it * 4;
        float4 y4;
#define STEP3(X, J) { \
        float dvx = dv.X; float t1 = dvx * uv.X; \
        const float4* bp = (const float4*)(sBq + (lb + J) * 32); \
        const float4* cp = (const float4*)(sCq + (lb + J) * 32); \
        float4 b0 = bp[0], b1 = bp[1], c0 = cp[0], c1 = cp[1]; \
        float e, yy; \
        e = __builtin_amdgcn_exp2f(dvx * A2[0]); xs[0] = fmaf(e, xs[0], t1 * b0.x); yy = xs[0] * c0.x; \
        e = __builtin_amdgcn_exp2f(dvx * A2[1]); xs[1] = fmaf(e, xs[1], t1 * b0.y); yy = fmaf(xs[1], c0.y, yy); \
        e = __builtin_amdgcn_exp2f(dvx * A2[2]); xs[2] = fmaf(e, xs[2], t1 * b0.z); yy = fmaf(xs[2], c0.z, yy); \
        e = __builtin_amdgcn_exp2f(dvx * A2[3]); xs[3] = fmaf(e, xs[3], t1 * b0.w); yy = fmaf(xs[3], c0.w, yy); \
        e = __builtin_amdgcn_exp2f(dvx * A2[4]); xs[4] = fmaf(e, xs[4], t1 * b1.x); yy = fmaf(xs[4], c1.x, yy); \
        e = __builtin_amdgcn_exp2f(dvx * A2[5]); xs[5] = fmaf(e, xs[5], t1 * b1.y); yy = fmaf(xs[5], c1.y, yy); \
        e = __builtin_amdgcn_exp2f(dvx * A2[6]); xs[6] = fmaf(e, xs[6], t1 * b1.z); yy = fmaf(xs[6], c1.z, yy); \
        e = __builtin_amdgcn_exp2f(dvx * A2[7]); xs[7] = fmaf(e, xs[7], t1 * b1.w); yy = fmaf(xs[7], c1.w, yy); \
        yy += __shfl_xor(yy, 1, 4); yy += __shfl_xor(yy, 2, 4); \
        y4.X = fmaf(uv.X, Dp, yy); }
        STEP3(x, 0) STEP3(y, 1) STEP3(z, 2) STEP3(w, 3)
#undef STEP3
        if (q == 0) *(float4*)(yp + it * 4) = y4;
        dv = dvn; uv = uvn;
    }
}

// ---------------- gate (y * silu(res)) + out_proj (256 -> 128) + residual ----------------
__global__ void k_gate_outproj(const float* __restrict__ yT, const float* __restrict__ resb,
                               const float* __restrict__ W,  // [256,128]
                               float* __restrict__ h) {
    __shared__ float g[32][257];
    int blk = blockIdx.x;
    int b = blk >> 6, tile = blk & 63;
    int l0 = tile * 32;
    int t = threadIdx.x;
    for (int idx = t; idx < 2048; idx += 256) {
        int k = idx >> 3, li = (idx & 7) * 4;
        float4 v = *(const float4*)(yT + ((size_t)(b * DIN + k)) * LL + l0 + li);
        g[li][k] = v.x; g[li + 1][k] = v.y; g[li + 2][k] = v.z; g[li + 3][k] = v.w;
    }
    __syncthreads();
    for (int i = t; i < 32 * DIN; i += 256) {
        int r = i >> 8, k = i & 255;
        float rv = resb[((size_t)b * LL + l0 + r) * DIN + k];
        g[r][k] *= rv / (1.f + __expf(-rv));
    }
    __syncthreads();
    int col = t & 127, rg = t >> 7;
    float acc[16];
    #pragma unroll
    for (int i = 0; i < 16; i++) acc[i] = 0.f;
    for (int k = 0; k < DIN; k++) {
        float w = W[k * DM + col];
        #pragma unroll
        for (int i = 0; i < 16; i++) acc[i] = fmaf(g[rg * 16 + i][k], w, acc[i]);
    }
    for (int i = 0; i < 16; i++) {
        size_t r = (size_t)b * LL + l0 + rg * 16 + i;
        h[r * DM + col] += acc[i];
    }
}

// ---------------- final: rmsnorm + out_w (128 -> 7) + denorm ----------------
__global__ void k_final(const float* __restrict__ h, const float* __restrict__ onw,
                        const float* __restrict__ outw, const float* __restrict__ stats,
                        float* __restrict__ out) {
    int bl = blockIdx.x;
    int b = bl >> 11;
    int t = threadIdx.x;   // 128
    __shared__ float xn[DM];
    __shared__ float red[2];
    float v = h[(size_t)bl * DM + t];
    float s = v * v;
    #pragma unroll
    for (int m = 32; m >= 1; m >>= 1) s += __shfl_xor(s, m, 64);
    if ((t & 63) == 0) red[t >> 6] = s;
    __syncthreads();
    float rms = rsqrtf((red[0] + red[1]) / (float)DM + 1e-5f);
    xn[t] = v * rms * onw[t];
    __syncthreads();
    if (t < 112) {
        int ccol = t >> 4, p = t & 15;
        float acc = 0.f;
        #pragma unroll
        for (int i = 0; i < 8; i++) { int k = p * 8 + i; acc = fmaf(xn[k], outw[k * 7 + ccol], acc); }
        #pragma unroll
        for (int m = 8; m >= 1; m >>= 1) acc += __shfl_xor(acc, m, 16);
        if (p == 0) {
            float sd = stats[112 + b * CIN + ccol], mn = stats[b * CIN + ccol];
            out[(size_t)bl * 7 + ccol] = acc * sd + mn;
        }
    }
}

extern "C" void kernel_launch(void* const* d_in, const int* in_sizes, int n_in,
                              void* d_out, int out_size, void* d_ws, size_t ws_size,
                              hipStream_t stream) {
    const float* x_enc = (const float*)d_in[0];
    const float* xmark = (const float*)d_in[1];
    const float* tokw  = (const float*)d_in[2];
    const float* timew = (const float*)d_in[3];
    const float* normw = (const float*)d_in[4];
    const float* inw   = (const float*)d_in[5];
    const float* cw    = (const float*)d_in[6];
    const float* cb    = (const float*)d_in[7];
    const float* xpw   = (const float*)d_in[8];
    const float* dtw   = (const float*)d_in[9];
    const float* dtb   = (const float*)d_in[10];
    const float* alog  = (const float*)d_in[11];
    const float* dpar  = (const float*)d_in[12];
    const float* opw   = (const float*)d_in[13];
    const float* onw   = (const float*)d_in[14];
    const float* outw  = (const float*)d_in[15];

    float* ws = (float*)d_ws;
    const size_t BL = (size_t)BB * LL;          // 32768
    float* stats  = ws;                          // 256
    float* h      = stats + 256;                 // BL*128
    float* xiraw  = h + BL * DM;                 // BL*256  (reused as Pb, then yT)
    float* resb   = xiraw + BL * DIN;            // BL*256
    float* xiT    = resb + BL * DIN;             // BL*256  [b,d,l]
    float* deltaT = xiT + BL * DIN;              // BL*256  [b,d,l]
    float* dtbuf  = deltaT + BL * DIN;           // BL*8
    float* BT     = dtbuf + BL * DTR;            // BL*32   [b,n,l]
    float* CT     = BT + BL * DFF;               // BL*32   [b,n,l]
    float* Xfb    = CT + BL * DFF;               // 16*NCH*8192 = 4.19M
    float* Pb     = xiraw;                       // alias: dead between k_conv and p3's yT write

    k_stats<<<BB * CIN, 256, 0, stream>>>(x_enc, stats);
    k_embed<<<(int)BL, DM, 0, stream>>>(x_enc, xmark, tokw, timew, stats, h);

    for (int i = 0; i < 2; i++) {
        k_rms_inproj<<<(int)(BL / ROWS_IN), 256, 0, stream>>>(
            h, normw + i * DM, inw + (size_t)i * DM * 512, xiraw, resb);
        k_conv<<<BB * 64, 256, 0, stream>>>(xiraw, cw + i * DIN * 4, cb + i * DIN, xiT);
        k_xproj<<<BB * 64, 256, 0, stream>>>(xiT, xpw + (size_t)i * DIN * NDBL, dtbuf, BT, CT);
        k_delta<<<BB * 64, 256, 0, stream>>>(dtbuf, dtw + i * DTR * DIN, dtb + i * DIN, deltaT);
        k_scan_p1<<<BB * NCH * 4, 256, 0, stream>>>(deltaT, xiT, BT,
                                                    alog + i * DIN * DFF, Pb, Xfb);
        k_scan_p2<<<BB * 8192 / 256, 256, 0, stream>>>(Pb, Xfb);
        k_scan_p3<<<BB * NCH * 4, 256, 0, stream>>>(deltaT, xiT, BT, CT, Xfb,
                                                    alog + i * DIN * DFF, dpar + i * DIN, xiraw);
        k_gate_outproj<<<BB * 64, 256, 0, stream>>>(xiraw, resb,
                                                    opw + (size_t)i * DIN * DM, h);
    }
    k_final<<<(int)BL, DM, 0, stream>>>(h, onw, outw, stats, (float*)d_out);
}

// Round 4
// 730.892 us; speedup vs baseline: 2.9248x; 1.2019x over previous
//
#include <hip/hip_runtime.h>
#include <hip/hip_bf16.h>
#include <math.h>

#define BB 16
#define LL 2048
#define CIN 7
#define DM 128
#define DIN 256
#define DFF 32
#define DTR 8
#define NDBL 72
#define NCH 32
#define CHUNK 64   // LL / NCH

// ---------------- stats: mean/std per (b,c) over L ----------------
__global__ void k_stats(const float* __restrict__ x, float* __restrict__ stats) {
    int bc = blockIdx.x;            // 0..111
    int b = bc / CIN, c = bc % CIN;
    const float* p = x + (size_t)b * LL * CIN + c;
    float s = 0.f, s2 = 0.f;
    for (int l = threadIdx.x; l < LL; l += blockDim.x) {
        float v = p[(size_t)l * CIN];
        s += v; s2 += v * v;
    }
    #pragma unroll
    for (int m = 32; m >= 1; m >>= 1) { s += __shfl_xor(s, m, 64); s2 += __shfl_xor(s2, m, 64); }
    __shared__ float sh[2][4];
    int wid = threadIdx.x >> 6, lane = threadIdx.x & 63;
    if (lane == 0) { sh[0][wid] = s; sh[1][wid] = s2; }
    __syncthreads();
    if (threadIdx.x == 0) {
        float S = 0.f, S2 = 0.f;
        for (int w = 0; w < 4; w++) { S += sh[0][w]; S2 += sh[1][w]; }
        float mean = S / (float)LL;
        float var = S2 / (float)LL - mean * mean;
        stats[bc] = mean;
        stats[112 + bc] = sqrtf(var + 1e-5f);
    }
}

// ---------------- embedding: token conv (circular) + time proj + PE ----------------
__global__ void k_embed(const float* __restrict__ x, const float* __restrict__ xmark,
                        const float* __restrict__ tokw, const float* __restrict__ timew,
                        const float* __restrict__ stats, float* __restrict__ h) {
    int bl = blockIdx.x;
    int b = bl >> 11, l = bl & (LL - 1);
    int d = threadIdx.x;   // 128
    __shared__ float xs[3][CIN];
    if (threadIdx.x < 21) {
        int k = threadIdx.x / CIN, c = threadIdx.x % CIN;
        int ll = (l - 1 + k + LL) & (LL - 1);
        float v = x[((size_t)b * LL + ll) * CIN + c];
        xs[k][c] = (v - stats[b * CIN + c]) / stats[112 + b * CIN + c];
    }
    __syncthreads();
    float acc = 0.f;
    #pragma unroll
    for (int c = 0; c < CIN; c++)
        #pragma unroll
        for (int k = 0; k < 3; k++)
            acc += tokw[d * 21 + c * 3 + k] * xs[k][c];
    #pragma unroll
    for (int j = 0; j < 4; j++) acc += xmark[(size_t)bl * 4 + j] * timew[j * DM + d];
    float div = expf(-(float)(d & ~1) * (9.2103403719761836f / 128.f));
    float ang = (float)l * div;
    acc += (d & 1) ? cosf(ang) : sinf(ang);
    h[(size_t)bl * DM + d] = acc;
}

// ---------------- rmsnorm + in_proj GEMM (128 -> 512), LDS-tiled ----------------
// block: 256 thr; 32 rows; thread tile 8r x 8c
__global__ void k_rms_inproj(const float* __restrict__ h, const float* __restrict__ normw,
                             const float* __restrict__ W,  // [128,512]
                             float* __restrict__ xiraw, float* __restrict__ res) {
    __shared__ float aT[DM][36];     // [k][r], padded
    __shared__ float sW[16][512];    // k-tile
    __shared__ float rmsA[32];
    int r0 = blockIdx.x * 32;
    int t = threadIdx.x;
    // stage h * normw, transposed
    #pragma unroll
    for (int i = 0; i < 16; ++i) {
        int lin = t + i * 256;
        int rr = lin >> 7, k = lin & 127;
        aT[k][rr] = h[(size_t)(r0 + rr) * DM + k] * normw[k];
    }
    // rms per row (raw h re-read, L1-hot)
    {
        int rr = t >> 3, p = t & 7;
        const float* hp = h + (size_t)(r0 + rr) * DM + p * 16;
        float s = 0.f;
        #pragma unroll
        for (int i = 0; i < 4; ++i) {
            float4 v = *(const float4*)(hp + i * 4);
            s += v.x * v.x + v.y * v.y + v.z * v.z + v.w * v.w;
        }
        s += __shfl_xor(s, 4, 8); s += __shfl_xor(s, 2, 8); s += __shfl_xor(s, 1, 8);
        if (p == 0) rmsA[rr] = rsqrtf(s / (float)DM + 1e-5f);
    }
    int r0t = (t >> 6) * 8, c0 = (t & 63) * 8;
    float acc[8][8];
    #pragma unroll
    for (int i = 0; i < 8; i++)
        #pragma unroll
        for (int j = 0; j < 8; j++) acc[i][j] = 0.f;
    for (int kt = 0; kt < 8; ++kt) {
        __syncthreads();
        #pragma unroll
        for (int i = 0; i < 8; ++i) {
            int lin4 = t + i * 256;
            int row = lin4 >> 7, c4 = (lin4 & 127) * 4;
            *(float4*)&sW[row][c4] = *(const float4*)&W[(size_t)(kt * 16 + row) * 512 + c4];
        }
        __syncthreads();
        #pragma unroll
        for (int kk = 0; kk < 16; ++kk) {
            float4 a0 = *(const float4*)&aT[kt * 16 + kk][r0t];
            float4 a1 = *(const float4*)&aT[kt * 16 + kk][r0t + 4];
            float4 w0 = *(const float4*)&sW[kk][c0];
            float4 w1 = *(const float4*)&sW[kk][c0 + 4];
            float av[8] = {a0.x, a0.y, a0.z, a0.w, a1.x, a1.y, a1.z, a1.w};
            float wv[8] = {w0.x, w0.y, w0.z, w0.w, w1.x, w1.y, w1.z, w1.w};
            #pragma unroll
            for (int ri = 0; ri < 8; ++ri)
                #pragma unroll
                for (int cj = 0; cj < 8; ++cj)
                    acc[ri][cj] = fmaf(av[ri], wv[cj], acc[ri][cj]);
        }
    }
    #pragma unroll
    for (int ri = 0; ri < 8; ++ri) {
        float rs = rmsA[r0t + ri];
        size_t row = (size_t)(r0 + r0t + ri);
        float4 o0 = {acc[ri][0] * rs, acc[ri][1] * rs, acc[ri][2] * rs, acc[ri][3] * rs};
        float4 o1 = {acc[ri][4] * rs, acc[ri][5] * rs, acc[ri][6] * rs, acc[ri][7] * rs};
        if (c0 < 256) {
            *(float4*)(xiraw + row * DIN + c0) = o0;
            *(float4*)(xiraw + row * DIN + c0 + 4) = o1;
        } else {
            *(float4*)(res + row * DIN + (c0 - 256)) = o0;
            *(float4*)(res + row * DIN + (c0 - 252)) = o1;
        }
    }
}

// ---------------- fused: conv+silu -> xiT ; x_proj -> BT,CT ; dt_proj+softplus -> dT ----------------
__global__ void k_front(const float* __restrict__ xiraw, const float* __restrict__ cw,
                        const float* __restrict__ cb, const float* __restrict__ xpw,
                        const float* __restrict__ dtw, const float* __restrict__ dtb,
                        float* __restrict__ xiT, float* __restrict__ BT,
                        float* __restrict__ CT, float* __restrict__ dT) {
    __shared__ float a[32][260];     // [l][d], padded (stride 260: f4-aligned, conflict-free GEMM reads)
    __shared__ float sWT[72][36];    // x_proj W^T k-tile: [col][k]
    __shared__ float sdt[32][8];
    int blk = blockIdx.x;
    int b = blk >> 6, tile = blk & 63;
    int l0 = tile * 32;
    int t = threadIdx.x;
    // conv + silu
    float4 w = ((const float4*)cw)[t];
    float bias = cb[t];
    float wdt[8];
    #pragma unroll
    for (int j = 0; j < 8; j++) wdt[j] = dtw[j * DIN + t];
    float dtbv = dtb[t];
    const float* base = xiraw + ((size_t)b * LL) * DIN + t;
    float w0 = 0.f, w1 = 0.f, w2 = 0.f;
    if (tile > 0) {
        w0 = base[(size_t)(l0 - 3) * DIN];
        w1 = base[(size_t)(l0 - 2) * DIN];
        w2 = base[(size_t)(l0 - 1) * DIN];
    }
    for (int ll = 0; ll < 32; ++ll) {
        float cur = base[(size_t)(l0 + ll) * DIN];
        float acc = fmaf(w.x, w0, bias);
        acc = fmaf(w.y, w1, acc);
        acc = fmaf(w.z, w2, acc);
        acc = fmaf(w.w, cur, acc);
        a[ll][t] = acc / (1.f + __expf(-acc));
        w0 = w1; w1 = w2; w2 = cur;
    }
    __syncthreads();
    // write xiT [b,d,l]
    for (int idx = t; idx < 2048; idx += 256) {
        int d = idx >> 3, li = (idx & 7) * 4;
        float4 v = { a[li][d], a[li + 1][d], a[li + 2][d], a[li + 3][d] };
        *(float4*)(xiT + ((size_t)(b * DIN + d)) * LL + l0 + li) = v;
    }
    // x_proj GEMM: K=256 in 8 tiles of 32
    int r = t >> 3, g = t & 7;
    float acc9[9];
    #pragma unroll
    for (int j = 0; j < 9; j++) acc9[j] = 0.f;
    for (int kt = 0; kt < 8; ++kt) {
        __syncthreads();
        for (int idx = t; idx < 72 * 32; idx += 256) {
            int c = idx % 72, kk = idx / 72;
            sWT[c][kk] = xpw[(size_t)(kt * 32 + kk) * NDBL + c];
        }
        __syncthreads();
        #pragma unroll
        for (int kk = 0; kk < 32; kk += 4) {
            float4 av = *(const float4*)&a[r][kt * 32 + kk];
            #pragma unroll
            for (int j = 0; j < 9; j++) {
                float4 wv = *(const float4*)&sWT[g * 9 + j][kk];
                acc9[j] = fmaf(av.x, wv.x, acc9[j]);
                acc9[j] = fmaf(av.y, wv.y, acc9[j]);
                acc9[j] = fmaf(av.z, wv.z, acc9[j]);
                acc9[j] = fmaf(av.w, wv.w, acc9[j]);
            }
        }
    }
    // scatter: dt cols -> sdt (LDS), B/C cols -> BT/CT [b,n,l]
    size_t rowl = (size_t)b * LL + l0 + r;  (void)rowl;
    #pragma unroll
    for (int j = 0; j < 9; j++) {
        int cg = g * 9 + j;
        float v = acc9[j];
        if (cg < DTR)            sdt[r][cg] = v;
        else if (cg < DTR + DFF) BT[((size_t)(b * DFF + cg - DTR)) * LL + l0 + r] = v;
        else                     CT[((size_t)(b * DFF + cg - DTR - DFF)) * LL + l0 + r] = v;
    }
    __syncthreads();
    // dt_proj + softplus -> a[l][d] (reuse)
    for (int rr = 0; rr < 32; ++rr) {
        float accd = dtbv;
        #pragma unroll
        for (int j = 0; j < 8; j++) accd = fmaf(sdt[rr][j], wdt[j], accd);
        a[rr][t] = (accd > 20.f) ? accd : log1pf(__expf(accd));
    }
    __syncthreads();
    // write dT [b,d,l]
    for (int idx = t; idx < 2048; idx += 256) {
        int d = idx >> 3, li = (idx & 7) * 4;
        float4 v = { a[li][d], a[li + 1][d], a[li + 2][d], a[li + 3][d] };
        *(float4*)(dT + ((size_t)(b * DIN + d)) * LL + l0 + li) = v;
    }
}

// ---------------- scan pass 1: 8 states/thread, B staged in LDS ----------------
__global__ void k_scan_p1(const float* __restrict__ dT, const float* __restrict__ uT,
                          const float* __restrict__ BT, const float* __restrict__ alog,
                          float* __restrict__ Pb, float* __restrict__ Xfb) {
    __shared__ float sB[CHUNK][32];
    int blk = blockIdx.x;
    int dblk = blk & 3;
    int c = (blk >> 2) & (NCH - 1);
    int b = blk >> 7;
    int t = threadIdx.x;
    int q = t & 3, dloc = t >> 2;
    int d = dblk * 64 + dloc;
    int l0 = c * CHUNK;
    for (int idx = t; idx < 32 * (CHUNK / 4); idx += 256) {
        int n = idx >> 4, lf = idx & 15;
        float4 v = *(const float4*)(BT + ((size_t)(b * DFF + n)) * LL + l0 + lf * 4);
        sB[lf * 4 + 0][n] = v.x; sB[lf * 4 + 1][n] = v.y;
        sB[lf * 4 + 2][n] = v.z; sB[lf * 4 + 3][n] = v.w;
    }
    float A2[8];
    {
        const float* ap = alog + d * DFF + q * 8;
        #pragma unroll
        for (int k = 0; k < 8; k++) A2[k] = -__expf(ap[k]) * 1.4426950408889634f;
    }
    const float* dp = dT + ((size_t)(b * DIN + d)) * LL + l0;
    const float* up = uT + ((size_t)(b * DIN + d)) * LL + l0;
    float4 dv = *(const float4*)dp, uv = *(const float4*)up;
    float xs[8] = {0, 0, 0, 0, 0, 0, 0, 0};
    float sdv = 0.f;
    const float* sBq = &sB[0][0] + q * 8;
    __syncthreads();
    for (int it = 0; it < CHUNK / 4; ++it) {
        int pit = (it + 1 < CHUNK / 4) ? it + 1 : it;
        float4 dvn = *(const float4*)(dp + pit * 4);
        float4 uvn = *(const float4*)(up + pit * 4);
        int lb = it * 4;
#define STEP1(X, J) { \
        float dvx = dv.X; sdv += dvx; float t1 = dvx * uv.X; \
        const float4* bp = (const float4*)(sBq + (lb + J) * 32); \
        float4 b0 = bp[0], b1 = bp[1]; \
        float e; \
        e = __builtin_amdgcn_exp2f(dvx * A2[0]); xs[0] = fmaf(e, xs[0], t1 * b0.x); \
        e = __builtin_amdgcn_exp2f(dvx * A2[1]); xs[1] = fmaf(e, xs[1], t1 * b0.y); \
        e = __builtin_amdgcn_exp2f(dvx * A2[2]); xs[2] = fmaf(e, xs[2], t1 * b0.z); \
        e = __builtin_amdgcn_exp2f(dvx * A2[3]); xs[3] = fmaf(e, xs[3], t1 * b0.w); \
        e = __builtin_amdgcn_exp2f(dvx * A2[4]); xs[4] = fmaf(e, xs[4], t1 * b1.x); \
        e = __builtin_amdgcn_exp2f(dvx * A2[5]); xs[5] = fmaf(e, xs[5], t1 * b1.y); \
        e = __builtin_amdgcn_exp2f(dvx * A2[6]); xs[6] = fmaf(e, xs[6], t1 * b1.z); \
        e = __builtin_amdgcn_exp2f(dvx * A2[7]); xs[7] = fmaf(e, xs[7], t1 * b1.w); }
        STEP1(x, 0) STEP1(y, 1) STEP1(z, 2) STEP1(w, 3)
#undef STEP1
        dv = dvn; uv = uvn;
    }
    size_t o = ((size_t)((b * NCH + c) * DIN + d)) * DFF + q * 8;
    float4 P0, P1, X0, X1;
    P0.x = __builtin_amdgcn_exp2f(A2[0] * sdv); P0.y = __builtin_amdgcn_exp2f(A2[1] * sdv);
    P0.z = __builtin_amdgcn_exp2f(A2[2] * sdv); P0.w = __builtin_amdgcn_exp2f(A2[3] * sdv);
    P1.x = __builtin_amdgcn_exp2f(A2[4] * sdv); P1.y = __builtin_amdgcn_exp2f(A2[5] * sdv);
    P1.z = __builtin_amdgcn_exp2f(A2[6] * sdv); P1.w = __builtin_amdgcn_exp2f(A2[7] * sdv);
    X0.x = xs[0]; X0.y = xs[1]; X0.z = xs[2]; X0.w = xs[3];
    X1.x = xs[4]; X1.y = xs[5]; X1.z = xs[6]; X1.w = xs[7];
    *(float4*)(Pb + o) = P0;  *(float4*)(Pb + o + 4) = P1;
    *(float4*)(Xfb + o) = X0; *(float4*)(Xfb + o + 4) = X1;
}

// ---------------- scan pass 2: combine chunk carries ----------------
__global__ void k_scan_p2(const float* __restrict__ Pb, float* __restrict__ Xfb) {
    int idx = blockIdx.x * 256 + threadIdx.x;   // 16*8192
    int b = idx >> 13;
    int dn = idx & 8191;
    float carry = 0.f;
    #pragma unroll
    for (int c = 0; c < NCH; ++c) {
        size_t o = ((size_t)(b * NCH + c) << 13) + dn;
        float P = Pb[o], xf = Xfb[o];
        Xfb[o] = carry;
        carry = fmaf(P, carry, xf);
    }
}

// ---------------- scan pass 3: 8 states/thread, B/C in LDS, quad-reduce y ----------------
__global__ void k_scan_p3(const float* __restrict__ dT, const float* __restrict__ uT,
                          const float* __restrict__ BT, const float* __restrict__ CT,
                          const float* __restrict__ Xfb, const float* __restrict__ alog,
                          const float* __restrict__ dparam, float* __restrict__ yT) {
    __shared__ float sB[CHUNK][32];
    __shared__ float sC[CHUNK][32];
    int blk = blockIdx.x;
    int dblk = blk & 3;
    int c = (blk >> 2) & (NCH - 1);
    int b = blk >> 7;
    int t = threadIdx.x;
    int q = t & 3, dloc = t >> 2;
    int d = dblk * 64 + dloc;
    int l0 = c * CHUNK;
    for (int idx = t; idx < 2 * 32 * (CHUNK / 4); idx += 256) {
        int sel = idx >> 9, rr = idx & 511;
        int n = rr >> 4, lf = rr & 15;
        const float* src = (sel ? CT : BT) + ((size_t)(b * DFF + n)) * LL + l0 + lf * 4;
        float4 v = *(const float4*)src;
        if (sel) { sC[lf*4+0][n] = v.x; sC[lf*4+1][n] = v.y; sC[lf*4+2][n] = v.z; sC[lf*4+3][n] = v.w; }
        else     { sB[lf*4+0][n] = v.x; sB[lf*4+1][n] = v.y; sB[lf*4+2][n] = v.z; sB[lf*4+3][n] = v.w; }
    }
    float A2[8];
    {
        const float* ap = alog + d * DFF + q * 8;
        #pragma unroll
        for (int k = 0; k < 8; k++) A2[k] = -__expf(ap[k]) * 1.4426950408889634f;
    }
    float Dp = dparam[d];
    const float* dp = dT + ((size_t)(b * DIN + d)) * LL + l0;
    const float* up = uT + ((size_t)(b * DIN + d)) * LL + l0;
    float* yp = yT + ((size_t)(b * DIN + d)) * LL + l0;
    size_t o = ((size_t)((b * NCH + c) * DIN + d)) * DFF + q * 8;
    float4 x0 = *(const float4*)(Xfb + o), x1 = *(const float4*)(Xfb + o + 4);
    float xs[8] = {x0.x, x0.y, x0.z, x0.w, x1.x, x1.y, x1.z, x1.w};
    float4 dv = *(const float4*)dp, uv = *(const float4*)up;
    const float* sBq = &sB[0][0] + q * 8;
    const float* sCq = &sC[0][0] + q * 8;
    __syncthreads();
    for (int it = 0; it < CHUNK / 4; ++it) {
        int pit = (it + 1 < CHUNK / 4) ? it + 1 : it;
        float4 dvn = *(const float4*)(dp + pit * 4);
        float4 uvn = *(const float4*)(up + pit * 4);
        int lb = it * 4;
        float4 y4;
#define STEP3(X, J) { \
        float dvx = dv.X; float t1 = dvx * uv.X; \
        const float4* bp = (const float4*)(sBq + (lb + J) * 32); \
        const float4* cp = (const float4*)(sCq + (lb + J) * 32); \
        float4 b0 = bp[0], b1 = bp[1], c0 = cp[0], c1 = cp[1]; \
        float e, yy; \
        e = __builtin_amdgcn_exp2f(dvx * A2[0]); xs[0] = fmaf(e, xs[0], t1 * b0.x); yy = xs[0] * c0.x; \
        e = __builtin_amdgcn_exp2f(dvx * A2[1]); xs[1] = fmaf(e, xs[1], t1 * b0.y); yy = fmaf(xs[1], c0.y, yy); \
        e = __builtin_amdgcn_exp2f(dvx * A2[2]); xs[2] = fmaf(e, xs[2], t1 * b0.z); yy = fmaf(xs[2], c0.z, yy); \
        e = __builtin_amdgcn_exp2f(dvx * A2[3]); xs[3] = fmaf(e, xs[3], t1 * b0.w); yy = fmaf(xs[3], c0.w, yy); \
        e = __builtin_amdgcn_exp2f(dvx * A2[4]); xs[4] = fmaf(e, xs[4], t1 * b1.x); yy = fmaf(xs[4], c1.x, yy); \
        e = __builtin_amdgcn_exp2f(dvx * A2[5]); xs[5] = fmaf(e, xs[5], t1 * b1.y); yy = fmaf(xs[5], c1.y, yy); \
        e = __builtin_amdgcn_exp2f(dvx * A2[6]); xs[6] = fmaf(e, xs[6], t1 * b1.z); yy = fmaf(xs[6], c1.z, yy); \
        e = __builtin_amdgcn_exp2f(dvx * A2[7]); xs[7] = fmaf(e, xs[7], t1 * b1.w); yy = fmaf(xs[7], c1.w, yy); \
        yy += __shfl_xor(yy, 1, 4); yy += __shfl_xor(yy, 2, 4); \
        y4.X = fmaf(uv.X, Dp, yy); }
        STEP3(x, 0) STEP3(y, 1) STEP3(z, 2) STEP3(w, 3)
#undef STEP3
        if (q == 0) *(float4*)(yp + it * 4) = y4;
        dv = dvn; uv = uvn;
    }
}

// ---------------- gate (y * silu(res)) + out_proj (256 -> 128) + residual, LDS-tiled ----------------
__global__ void k_gate_outproj(const float* __restrict__ yT, const float* __restrict__ resb,
                               const float* __restrict__ W,  // [256,128]
                               float* __restrict__ h) {
    __shared__ float gT[256][36];    // [k][r]
    __shared__ float sW[16][128];
    int blk = blockIdx.x;
    int b = blk >> 6, tile = blk & 63;
    int l0 = tile * 32;
    int t = threadIdx.x;
    // stage yT (natural transpose: float4 along l)
    #pragma unroll
    for (int i = 0; i < 8; ++i) {
        int lin4 = t + i * 256;
        int d = lin4 >> 3, lq = (lin4 & 7) * 4;
        float4 v = *(const float4*)(yT + ((size_t)(b * DIN + d)) * LL + l0 + lq);
        *(float4*)&gT[d][lq] = v;
    }
    __syncthreads();
    // gate with silu(res)
    for (int rr = 0; rr < 32; ++rr) {
        float rv = resb[((size_t)b * LL + l0 + rr) * DIN + t];
        gT[t][rr] *= rv / (1.f + __expf(-rv));
    }
    int rg4 = (t >> 5) * 4, cg4 = (t & 31) * 4;
    float acc[4][4];
    #pragma unroll
    for (int i = 0; i < 4; i++)
        #pragma unroll
        for (int j = 0; j < 4; j++) acc[i][j] = 0.f;
    for (int kt = 0; kt < 16; ++kt) {
        __syncthreads();
        #pragma unroll
        for (int i = 0; i < 2; ++i) {
            int lin4 = t + i * 256;
            int row = lin4 >> 5, c4 = (lin4 & 31) * 4;
            *(float4*)&sW[row][c4] = *(const float4*)&W[(size_t)(kt * 16 + row) * DM + c4];
        }
        __syncthreads();
        #pragma unroll
        for (int kk = 0; kk < 16; ++kk) {
            float4 av = *(const float4*)&gT[kt * 16 + kk][rg4];
            float4 wv = *(const float4*)&sW[kk][cg4];
            float avv[4] = {av.x, av.y, av.z, av.w};
            float wvv[4] = {wv.x, wv.y, wv.z, wv.w};
            #pragma unroll
            for (int ri = 0; ri < 4; ++ri)
                #pragma unroll
                for (int cj = 0; cj < 4; ++cj)
                    acc[ri][cj] = fmaf(avv[ri], wvv[cj], acc[ri][cj]);
        }
    }
    #pragma unroll
    for (int ri = 0; ri < 4; ++ri) {
        size_t row = (size_t)b * LL + l0 + rg4 + ri;
        float4 cur = *(float4*)(h + row * DM + cg4);
        cur.x += acc[ri][0]; cur.y += acc[ri][1]; cur.z += acc[ri][2]; cur.w += acc[ri][3];
        *(float4*)(h + row * DM + cg4) = cur;
    }
}

// ---------------- final: rmsnorm + out_w (128 -> 7) + denorm ----------------
__global__ void k_final(const float* __restrict__ h, const float* __restrict__ onw,
                        const float* __restrict__ outw, const float* __restrict__ stats,
                        float* __restrict__ out) {
    int bl = blockIdx.x;
    int b = bl >> 11;
    int t = threadIdx.x;   // 128
    __shared__ float xn[DM];
    __shared__ float red[2];
    float v = h[(size_t)bl * DM + t];
    float s = v * v;
    #pragma unroll
    for (int m = 32; m >= 1; m >>= 1) s += __shfl_xor(s, m, 64);
    if ((t & 63) == 0) red[t >> 6] = s;
    __syncthreads();
    float rms = rsqrtf((red[0] + red[1]) / (float)DM + 1e-5f);
    xn[t] = v * rms * onw[t];
    __syncthreads();
    if (t < 112) {
        int ccol = t >> 4, p = t & 15;
        float acc = 0.f;
        #pragma unroll
        for (int i = 0; i < 8; i++) { int k = p * 8 + i; acc = fmaf(xn[k], outw[k * 7 + ccol], acc); }
        #pragma unroll
        for (int m = 8; m >= 1; m >>= 1) acc += __shfl_xor(acc, m, 16);
        if (p == 0) {
            float sd = stats[112 + b * CIN + ccol], mn = stats[b * CIN + ccol];
            out[(size_t)bl * 7 + ccol] = acc * sd + mn;
        }
    }
}

extern "C" void kernel_launch(void* const* d_in, const int* in_sizes, int n_in,
                              void* d_out, int out_size, void* d_ws, size_t ws_size,
                              hipStream_t stream) {
    const float* x_enc = (const float*)d_in[0];
    const float* xmark = (const float*)d_in[1];
    const float* tokw  = (const float*)d_in[2];
    const float* timew = (const float*)d_in[3];
    const float* normw = (const float*)d_in[4];
    const float* inw   = (const float*)d_in[5];
    const float* cw    = (const float*)d_in[6];
    const float* cb    = (const float*)d_in[7];
    const float* xpw   = (const float*)d_in[8];
    const float* dtw   = (const float*)d_in[9];
    const float* dtb   = (const float*)d_in[10];
    const float* alog  = (const float*)d_in[11];
    const float* dpar  = (const float*)d_in[12];
    const float* opw   = (const float*)d_in[13];
    const float* onw   = (const float*)d_in[14];
    const float* outw  = (const float*)d_in[15];

    float* ws = (float*)d_ws;
    const size_t BL = (size_t)BB * LL;          // 32768
    float* stats  = ws;                          // 256
    float* h      = stats + 256;                 // BL*128
    float* xiraw  = h + BL * DM;                 // BL*256  (reused as Pb, then yT)
    float* resb   = xiraw + BL * DIN;            // BL*256
    float* xiT    = resb + BL * DIN;             // BL*256  [b,d,l]
    float* deltaT = xiT + BL * DIN;              // BL*256  [b,d,l]
    float* dtbuf  = deltaT + BL * DIN;           // BL*8 (unused now)
    float* BT     = dtbuf + BL * DTR;            // BL*32   [b,n,l]
    float* CT     = BT + BL * DFF;               // BL*32   [b,n,l]
    float* Xfb    = CT + BL * DFF;               // 16*NCH*8192
    float* Pb     = xiraw;                       // alias: dead between k_front and p3's yT write

    k_stats<<<BB * CIN, 256, 0, stream>>>(x_enc, stats);
    k_embed<<<(int)BL, DM, 0, stream>>>(x_enc, xmark, tokw, timew, stats, h);

    for (int i = 0; i < 2; i++) {
        k_rms_inproj<<<(int)(BL / 32), 256, 0, stream>>>(
            h, normw + i * DM, inw + (size_t)i * DM * 512, xiraw, resb);
        k_front<<<BB * 64, 256, 0, stream>>>(xiraw, cw + i * DIN * 4, cb + i * DIN,
                                             xpw + (size_t)i * DIN * NDBL,
                                             dtw + i * DTR * DIN, dtb + i * DIN,
                                             xiT, BT, CT, deltaT);
        k_scan_p1<<<BB * NCH * 4, 256, 0, stream>>>(deltaT, xiT, BT,
                                                    alog + i * DIN * DFF, Pb, Xfb);
        k_scan_p2<<<BB * 8192 / 256, 256, 0, stream>>>(Pb, Xfb);
        k_scan_p3<<<BB * NCH * 4, 256, 0, stream>>>(deltaT, xiT, BT, CT, Xfb,
                                                    alog + i * DIN * DFF, dpar + i * DIN, xiraw);
        k_gate_outproj<<<BB * 64, 256, 0, stream>>>(xiraw, resb,
                                                    opw + (size_t)i * DIN * DM, h);
    }
    k_final<<<(int)BL, DM, 0, stream>>>(h, onw, outw, stats, (float*)d_out);
}